// Round 3
// baseline (4158.617 us; speedup 1.0000x reference)
//
#include <hip/hip_runtime.h>

typedef unsigned short u16;
typedef __attribute__((ext_vector_type(8))) short short8;
typedef __attribute__((ext_vector_type(4))) float f32x4;

#define B_   1024
#define S_   64
#define E_   100
#define H_   512
#define G3_  1536
#define XW_  256      /* Xs row: x1[128] | x2[128] */
#define WSZG (32 * 3 * 60 * 512)   /* Wswz elems per encoder = 2,949,120 */

__device__ __forceinline__ float bf2f(u16 u) {
    union { unsigned int u; float f; } c; c.u = ((unsigned int)u) << 16; return c.f;
}
__device__ __forceinline__ u16 f2bf(float f) {
    union { float f; unsigned int u; } c; c.f = f;
    unsigned int r = c.u + 0x7fffu + ((c.u >> 16) & 1u);
    return (u16)(r >> 16);
}
__device__ __forceinline__ f32x4 mfma16(short8 a, short8 b, f32x4 c) {
    return __builtin_amdgcn_mfma_f32_16x16x32_bf16(a, b, c, 0, 0, 0);
}

// ---------- embedding gather -> bf16 hi/lo pair planes, zero-padded to 128 --
__global__ __launch_bounds__(256) void gather_kernel(
    const int* __restrict__ tok, const float* __restrict__ emb, u16* __restrict__ xs)
{
    int tid = threadIdx.x;
    int hw  = tid & 31;
    int rowid = blockIdx.x * 8 + (tid >> 5);      // rowid = t*1024 + b
    int t = rowid >> 10, b = rowid & 1023;
    int token = tok[b * S_ + t];
    const float* src = emb + (long)token * E_;
    u16* dst = xs + (long)rowid * XW_;
    int c0 = hw * 4;
    u16 a1[4], a2[4];
    #pragma unroll
    for (int j = 0; j < 4; ++j) {
        int c = c0 + j;
        float v = (c < E_) ? src[c] : 0.f;
        u16 h = f2bf(v);
        a1[j] = h;
        a2[j] = f2bf(v - bf2f(h));
    }
    uint2 p1, p2;
    p1.x = (unsigned)a1[0] | ((unsigned)a1[1] << 16);
    p1.y = (unsigned)a1[2] | ((unsigned)a1[3] << 16);
    p2.x = (unsigned)a2[0] | ((unsigned)a2[1] << 16);
    p2.y = (unsigned)a2[2] | ((unsigned)a2[3] << 16);
    *(uint2*)(dst + c0)       = p1;
    *(uint2*)(dst + 128 + c0) = p2;
}

// ---------- weight repack straight into MFMA-fragment order -----------------
// Wswz[ht(32)][gate(3)][ks(60)][lane(64)][8] per encoder.
// Per-(lane,jj): n = ht*16 + (lane&15), k = ks*32 + (lane>>4)*8 + jj.
// k<384: three 128-col groups of wih (w1,w1,w2); k>=384: three 512-col groups
// of whh (w1,w1,w2). Matches A-side chunk order (x1,x2,x1 | h1,h2,h1).
__global__ __launch_bounds__(256) void repack_swz(
    const float* __restrict__ wih, const float* __restrict__ whh, u16* __restrict__ out)
{
    long idx = (long)blockIdx.x * 256 + threadIdx.x;   // over WSZG
    int jj   = idx & 7;
    int lane = (idx >> 3) & 63;
    int q9   = (int)(idx >> 9);
    int ks   = q9 % 60;
    int q    = q9 / 60;
    int gate = q % 3;
    int ht   = q / 3;
    int n   = ht * 16 + (lane & 15);
    int k   = ks * 32 + (lane >> 4) * 8 + jj;
    int row = gate * H_ + n;
    float w; int lo;
    if (k < 384) {
        int kk = k & 127, grp = k >> 7;
        if (kk >= E_) { out[idx] = 0; return; }
        w = wih[row * E_ + kk];
        lo = (grp == 2);
    } else {
        int kh = k - 384;
        int kk = kh & 511, grp = kh >> 9;
        w = whh[row * H_ + kk];
        lo = (grp == 2);
    }
    u16 h = f2bf(w);
    if (lo) h = f2bf(w - bf2f(h));
    out[idx] = h;
}

__global__ __launch_bounds__(256) void repack_lin(
    const float* __restrict__ lw, u16* __restrict__ l1, u16* __restrict__ l2)
{
    int i = blockIdx.x * 256 + threadIdx.x;       // over 512*512
    float w = lw[i];
    u16 h = f2bf(w);
    l1[i] = h;
    l2[i] = f2bf(w - bf2f(h));
}

// ---------- one GRU time step: LDS-free, barrier-free -----------------------
// Wave tile: 64 batch rows x 16 hidden cols x 3 gates. Block = 2 waves sharing
// the same (g,ht) B-fragment stream (L1 broadcast). Grid 768 = 3 blocks/CU.
struct BiasPtrs { const float* bih[3]; const float* bhh[3]; };

__global__ __launch_bounds__(128) void gru_step(
    const u16* __restrict__ xs,      // [3][64][1024][256]
    const u16* __restrict__ wswz,    // [3][WSZG]
    BiasPtrs bp,
    const u16* __restrict__ h1_in, const u16* __restrict__ h2_in,   // [3][1024][512]
    u16* __restrict__ h1_out, u16* __restrict__ h2_out,
    int t)
{
    const int wave = threadIdx.x >> 6, lane = threadIdx.x & 63;
    const int l15 = lane & 15, l4 = lane >> 4;
    const int bid = blockIdx.x;
    const int g   = bid >> 8;
    const int rem = bid & 255;
    const int ht  = rem >> 3;
    const int mb  = ((rem & 7) << 1) | wave;
    const int m0  = mb << 6;
    const int ko  = l4 * 8;

    const u16* wgr = wswz + (long)g * WSZG + ((long)(ht * 3 + 0) * 60) * 512 + lane * 8;
    const u16* wgz = wgr + 60 * 512;
    const u16* wgn = wgz + 60 * 512;
    const u16* xb  = xs + (long)(g * S_ + t) * B_ * XW_;
    const u16* hb1 = h1_in + (long)g * B_ * H_;
    const u16* hb2 = h2_in + (long)g * B_ * H_;

    int ro_x[4], ro_h[4];
    #pragma unroll
    for (int mt = 0; mt < 4; ++mt) {
        int r = m0 + mt * 16 + l15;
        ro_x[mt] = r * XW_;
        ro_h[mt] = r * H_;
    }

    f32x4 zero = {0.f, 0.f, 0.f, 0.f};
    f32x4 acc_r[4]  = {zero, zero, zero, zero};
    f32x4 acc_z[4]  = {zero, zero, zero, zero};
    f32x4 acc_ni[4] = {zero, zero, zero, zero};
    f32x4 acc_nh[4] = {zero, zero, zero, zero};

    // ---- x part: ks 0..11, cols (ks&7)*32 over x1,x2,x1 ----
    #pragma unroll 4
    for (int ks = 0; ks < 12; ++ks) {
        short8 br = *(const short8*)(wgr + ks * 512);
        short8 bz = *(const short8*)(wgz + ks * 512);
        short8 bn = *(const short8*)(wgn + ks * 512);
        int col = (ks & 7) * 32 + ko;
        short8 a0 = *(const short8*)(xb + ro_x[0] + col);
        short8 a1 = *(const short8*)(xb + ro_x[1] + col);
        short8 a2 = *(const short8*)(xb + ro_x[2] + col);
        short8 a3 = *(const short8*)(xb + ro_x[3] + col);
        acc_r[0] = mfma16(a0, br, acc_r[0]);  acc_r[1] = mfma16(a1, br, acc_r[1]);
        acc_r[2] = mfma16(a2, br, acc_r[2]);  acc_r[3] = mfma16(a3, br, acc_r[3]);
        acc_z[0] = mfma16(a0, bz, acc_z[0]);  acc_z[1] = mfma16(a1, bz, acc_z[1]);
        acc_z[2] = mfma16(a2, bz, acc_z[2]);  acc_z[3] = mfma16(a3, bz, acc_z[3]);
        acc_ni[0] = mfma16(a0, bn, acc_ni[0]); acc_ni[1] = mfma16(a1, bn, acc_ni[1]);
        acc_ni[2] = mfma16(a2, bn, acc_ni[2]); acc_ni[3] = mfma16(a3, bn, acc_ni[3]);
    }

    // ---- h part: three groups of 16 ks (h1*w1, h2*w1, h1*w2) ----
    const u16* srcs[3] = { hb1, hb2, hb1 };
    #pragma unroll
    for (int grp = 0; grp < 3; ++grp) {
        const u16* hb = srcs[grp];
        const u16* wr = wgr + (12 + grp * 16) * 512;
        const u16* wz = wgz + (12 + grp * 16) * 512;
        const u16* wn = wgn + (12 + grp * 16) * 512;
        #pragma unroll 4
        for (int kh = 0; kh < 16; ++kh) {
            short8 br = *(const short8*)(wr + kh * 512);
            short8 bz = *(const short8*)(wz + kh * 512);
            short8 bn = *(const short8*)(wn + kh * 512);
            int col = kh * 32 + ko;
            short8 a0 = *(const short8*)(hb + ro_h[0] + col);
            short8 a1 = *(const short8*)(hb + ro_h[1] + col);
            short8 a2 = *(const short8*)(hb + ro_h[2] + col);
            short8 a3 = *(const short8*)(hb + ro_h[3] + col);
            acc_r[0] = mfma16(a0, br, acc_r[0]);  acc_r[1] = mfma16(a1, br, acc_r[1]);
            acc_r[2] = mfma16(a2, br, acc_r[2]);  acc_r[3] = mfma16(a3, br, acc_r[3]);
            acc_z[0] = mfma16(a0, bz, acc_z[0]);  acc_z[1] = mfma16(a1, bz, acc_z[1]);
            acc_z[2] = mfma16(a2, bz, acc_z[2]);  acc_z[3] = mfma16(a3, bz, acc_z[3]);
            acc_nh[0] = mfma16(a0, bn, acc_nh[0]); acc_nh[1] = mfma16(a1, bn, acc_nh[1]);
            acc_nh[2] = mfma16(a2, bn, acc_nh[2]); acc_nh[3] = mfma16(a3, bn, acc_nh[3]);
        }
    }

    // ---- GRU pointwise epilogue (f32), h reconstructed from bf16 pair ----
    int hc = ht * 16 + l15;
    const float* bih = bp.bih[g];
    const float* bhh = bp.bhh[g];
    float b_ir = bih[hc],          b_hr = bhh[hc];
    float b_iz = bih[H_ + hc],     b_hz = bhh[H_ + hc];
    float b_in = bih[2 * H_ + hc], b_hn = bhh[2 * H_ + hc];
    #pragma unroll
    for (int mt = 0; mt < 4; ++mt) {
        #pragma unroll
        for (int i = 0; i < 4; ++i) {
            int m = m0 + mt * 16 + l4 * 4 + i;
            long idx = ((long)g * B_ + m) * H_ + hc;
            float pr = acc_r[mt][i] + b_ir + b_hr;
            float pz = acc_z[mt][i] + b_iz + b_hz;
            float vi = acc_ni[mt][i] + b_in;
            float vh = acc_nh[mt][i] + b_hn;
            float r = 1.f / (1.f + __expf(-pr));
            float z = 1.f / (1.f + __expf(-pz));
            float n = tanhf(vi + r * vh);
            float hold = bf2f(h1_in[idx]) + bf2f(h2_in[idx]);
            float hnew = (1.f - z) * n + z * hold;
            u16 hh = f2bf(hnew);
            h1_out[idx] = hh;
            h2_out[idx] = f2bf(hnew - bf2f(hh));
        }
    }
}

// ---------- qc = 0.5*(eq+ec) from bf16 pairs, split into bf16 pair ----------
__global__ __launch_bounds__(256) void qc_kernel(
    const u16* __restrict__ h1, const u16* __restrict__ h2,
    u16* __restrict__ q1, u16* __restrict__ q2)
{
    int i = blockIdx.x * 256 + threadIdx.x;       // over 1024*512
    float eq = bf2f(h1[i]) + bf2f(h2[i]);
    float ec = bf2f(h1[B_ * H_ + i]) + bf2f(h2[B_ * H_ + i]);
    float q = 0.5f * (eq + ec);
    u16 h = f2bf(q);
    q1[i] = h;
    q2[i] = f2bf(q - bf2f(h));
}

// ---------- generic NT GEMM with per-chunk source pointers ------------------
struct GArgs { const u16* a[24]; const u16* b[24]; };

__global__ __launch_bounds__(256) void gemm_nt(
    GArgs ga, int nch, int astr, int bstr,
    const float* __restrict__ bias, float* __restrict__ outf,
    u16* __restrict__ ohi, u16* __restrict__ olo, int ldc, int mode)
{
    __shared__ __attribute__((aligned(16))) u16 As[64 * 72];
    __shared__ __attribute__((aligned(16))) u16 Bs[64 * 72];
    const int tid = threadIdx.x;
    const int w = tid >> 6, lane = tid & 63;
    const int l15 = lane & 15, l4 = lane >> 4;
    const int m0 = blockIdx.x * 64, n0 = blockIdx.y * 64;

    f32x4 zero = {0.f, 0.f, 0.f, 0.f};
    f32x4 acc[4] = {zero, zero, zero, zero};

    for (int c = 0; c < nch; ++c) {
        int row = tid >> 2, seg = tid & 3;
        const u16* sa = ga.a[c] + (long)(m0 + row) * astr + seg * 16;
        *(uint4*)(&As[row * 72 + seg * 16])     = *(const uint4*)(sa);
        *(uint4*)(&As[row * 72 + seg * 16 + 8]) = *(const uint4*)(sa + 8);
        const u16* sb = ga.b[c] + (long)(n0 + row) * bstr + seg * 16;
        *(uint4*)(&Bs[row * 72 + seg * 16])     = *(const uint4*)(sb);
        *(uint4*)(&Bs[row * 72 + seg * 16 + 8]) = *(const uint4*)(sb + 8);
        __syncthreads();
        #pragma unroll
        for (int ks = 0; ks < 2; ++ks) {
            short8 bfrag = *(const short8*)(&Bs[(w * 16 + l15) * 72 + ks * 32 + l4 * 8]);
            #pragma unroll
            for (int rt = 0; rt < 4; ++rt) {
                short8 a = *(const short8*)(&As[(rt * 16 + l15) * 72 + ks * 32 + l4 * 8]);
                acc[rt] = mfma16(a, bfrag, acc[rt]);
            }
        }
        __syncthreads();
    }

    int n = n0 + w * 16 + l15;
    float bv = bias ? bias[n] : 0.f;
    #pragma unroll
    for (int rt = 0; rt < 4; ++rt) {
        #pragma unroll
        for (int i = 0; i < 4; ++i) {
            int m = m0 + rt * 16 + l4 * 4 + i;
            float v = acc[rt][i] + bv;
            if (mode == 0) {
                outf[(long)m * ldc + n] = v;
            } else {
                u16 h = f2bf(v);
                ohi[(long)m * ldc + n] = h;
                olo[(long)m * ldc + n] = f2bf(v - bf2f(h));
            }
        }
    }
}

// ---------- row softmax (1024 wide), f32 in/out -----------------------------
__global__ __launch_bounds__(256) void softmax_kernel(
    const float* __restrict__ lg, float* __restrict__ out)
{
    __shared__ float red[256];
    int row = blockIdx.x, tid = threadIdx.x;
    const float* src = lg + (long)row * 1024;
    float x[4];
    float mx = -1e30f;
    #pragma unroll
    for (int i = 0; i < 4; ++i) { x[i] = src[tid + 256 * i]; mx = fmaxf(mx, x[i]); }
    red[tid] = mx; __syncthreads();
    for (int s = 128; s > 0; s >>= 1) { if (tid < s) red[tid] = fmaxf(red[tid], red[tid + s]); __syncthreads(); }
    mx = red[0]; __syncthreads();
    float sm = 0.f;
    #pragma unroll
    for (int i = 0; i < 4; ++i) { x[i] = __expf(x[i] - mx); sm += x[i]; }
    red[tid] = sm; __syncthreads();
    for (int s = 128; s > 0; s >>= 1) { if (tid < s) red[tid] += red[tid + s]; __syncthreads(); }
    float inv = 1.f / red[0];
    float* dst = out + (long)row * 1024;
    #pragma unroll
    for (int i = 0; i < 4; ++i) dst[tid + 256 * i] = x[i] * inv;
}

// ---------------------------------------------------------------------------
extern "C" void kernel_launch(void* const* d_in, const int* in_sizes, int n_in,
                              void* d_out, int out_size, void* d_ws, size_t ws_size,
                              hipStream_t stream)
{
    const int* tok[3] = {(const int*)d_in[0], (const int*)d_in[1], (const int*)d_in[2]};
    const float *emb[3], *wih[3], *whh[3], *bih[3], *bhh[3];
    for (int g = 0; g < 3; ++g) {
        emb[g] = (const float*)d_in[3 + 5 * g];
        wih[g] = (const float*)d_in[4 + 5 * g];
        whh[g] = (const float*)d_in[5 + 5 * g];
        bih[g] = (const float*)d_in[6 + 5 * g];
        bhh[g] = (const float*)d_in[7 + 5 * g];
    }
    const float* lin_w = (const float*)d_in[18];
    const float* lin_b = (const float*)d_in[19];

    char* ws = (char*)d_ws;
    size_t off = 0;
    auto alloc = [&](size_t bytes) { void* p = ws + off; off += (bytes + 255) & ~255ull; return p; };

    const size_t BH  = (size_t)B_ * H_;           // 524288
    const size_t PRB = 3 * BH * 2;                // bf16 plane bytes (3.1 MB)
    const size_t PING = 2 * PRB;                  // h1+h2 per ping

    u16*   Xs   = (u16*)alloc(3ll * S_ * B_ * XW_ * 2);     // 100.7 MB
    u16*   Wswz = (u16*)alloc(3ll * WSZG * 2);              // 17.7 MB
    u16*   LW1  = (u16*)alloc((size_t)H_ * H_ * 2);
    u16*   LW2  = (u16*)alloc((size_t)H_ * H_ * 2);
    char*  HB   = (char*)alloc(2 * PING);                   // 12.6 MB
    u16*   QC1  = (u16*)alloc(BH * 2);
    u16*   QC2  = (u16*)alloc(BH * 2);
    u16*   EQ1  = (u16*)alloc(BH * 2);
    u16*   EQ2  = (u16*)alloc(BH * 2);
    float* LG   = (float*)alloc(3ll * B_ * B_ * 4);         // 12.6 MB

    u16* H1[2]; u16* H2[2];
    for (int i = 0; i < 2; ++i) {
        char* pb = HB + (size_t)i * PING;
        H1[i] = (u16*)pb;
        H2[i] = (u16*)(pb + PRB);
    }

    hipMemsetAsync(HB, 0, PING, stream);   // zero h0 (ping 0: both planes)

    for (int g = 0; g < 3; ++g) {
        gather_kernel<<<dim3(S_ * B_ / 8), 256, 0, stream>>>(tok[g], emb[g], Xs + (size_t)g * S_ * B_ * XW_);
        repack_swz<<<dim3(WSZG / 256), 256, 0, stream>>>(wih[g], whh[g], Wswz + (size_t)g * WSZG);
    }
    repack_lin<<<dim3(H_ * H_ / 256), 256, 0, stream>>>(lin_w, LW1, LW2);

    BiasPtrs bp;
    for (int g = 0; g < 3; ++g) { bp.bih[g] = bih[g]; bp.bhh[g] = bhh[g]; }

    int p = 0;
    for (int t = S_ - 1; t >= 0; --t) {
        gru_step<<<dim3(768), 128, 0, stream>>>(Xs, Wswz, bp,
            H1[p], H2[p], H1[1 - p], H2[1 - p], t);
        p ^= 1;
    }
    const u16* H1F = H1[p];
    const u16* H2F = H2[p];

    qc_kernel<<<dim3(BH / 256), 256, 0, stream>>>(H1F, H2F, QC1, QC2);

    // eqc = qc @ lin_w.T + lin_b : q1w1 + q2w1 + q1w2 (24 chunks over K=512)
    GArgs ga;
    for (int c = 0; c < 8; ++c)   { ga.a[c] = QC1 + c * 64;        ga.b[c] = LW1 + c * 64; }
    for (int c = 8; c < 16; ++c)  { ga.a[c] = QC2 + (c - 8) * 64;  ga.b[c] = LW1 + (c - 8) * 64; }
    for (int c = 16; c < 24; ++c) { ga.a[c] = QC1 + (c - 16) * 64; ga.b[c] = LW2 + (c - 16) * 64; }
    gemm_nt<<<dim3(16, 8), 256, 0, stream>>>(ga, 24, H_, H_, lin_b, nullptr, EQ1, EQ2, H_, 1);

    // sims: logits = X @ er.T via a1b1 + a2b1 + a1b2
    const u16* R1 = H1F + 2 * BH;
    const u16* R2 = H2F + 2 * BH;
    for (int g = 0; g < 3; ++g) {
        const u16 *A1, *A2;
        if (g == 0)      { A1 = H1F;      A2 = H2F; }
        else if (g == 1) { A1 = H1F + BH; A2 = H2F + BH; }
        else             { A1 = EQ1;      A2 = EQ2; }
        GArgs gs;
        for (int c = 0; c < 8; ++c)   { gs.a[c] = A1 + c * 64;        gs.b[c] = R1 + c * 64; }
        for (int c = 8; c < 16; ++c)  { gs.a[c] = A2 + (c - 8) * 64;  gs.b[c] = R1 + (c - 8) * 64; }
        for (int c = 16; c < 24; ++c) { gs.a[c] = A1 + (c - 16) * 64; gs.b[c] = R2 + (c - 16) * 64; }
        gemm_nt<<<dim3(16, 16), 256, 0, stream>>>(gs, 24, H_, H_, nullptr,
            LG + (size_t)g * B_ * B_, nullptr, nullptr, B_, 0);
    }

    softmax_kernel<<<dim3(3 * B_), 256, 0, stream>>>(LG, (float*)d_out);
}

// Round 4
// 3777.759 us; speedup vs baseline: 1.1008x; 1.1008x over previous
//
#include <hip/hip_runtime.h>

typedef unsigned short u16;
typedef __attribute__((ext_vector_type(8))) short short8;
typedef __attribute__((ext_vector_type(4))) float f32x4;

#define B_   1024
#define S_   64
#define E_   100
#define H_   512
#define G3_  1536
#define XW_  256      /* Xs row: x1[128] | x2[128] */
#define KW_  1920     /* Wcat row: w1ih(128) w1ih(128) w2ih(128) w1hh(512) w1hh(512) w2hh(512) */
#define NCH_ 30

__device__ __forceinline__ float bf2f(u16 u) {
    union { unsigned int u; float f; } c; c.u = ((unsigned int)u) << 16; return c.f;
}
__device__ __forceinline__ u16 f2bf(float f) {
    union { float f; unsigned int u; } c; c.f = f;
    unsigned int r = c.u + 0x7fffu + ((c.u >> 16) & 1u);
    return (u16)(r >> 16);
}
__device__ __forceinline__ f32x4 mfma16(short8 a, short8 b, f32x4 c) {
    return __builtin_amdgcn_mfma_f32_16x16x32_bf16(a, b, c, 0, 0, 0);
}

// ---------- embedding gather -> bf16 hi/lo pair planes, zero-padded to 128 --
__global__ __launch_bounds__(256) void gather_kernel(
    const int* __restrict__ tok, const float* __restrict__ emb, u16* __restrict__ xs)
{
    int tid = threadIdx.x;
    int hw  = tid & 31;
    int rowid = blockIdx.x * 8 + (tid >> 5);      // rowid = t*1024 + b
    int t = rowid >> 10, b = rowid & 1023;
    int token = tok[b * S_ + t];
    const float* src = emb + (long)token * E_;
    u16* dst = xs + (long)rowid * XW_;
    int c0 = hw * 4;
    u16 a1[4], a2[4];
    #pragma unroll
    for (int j = 0; j < 4; ++j) {
        int c = c0 + j;
        float v = (c < E_) ? src[c] : 0.f;
        u16 h = f2bf(v);
        a1[j] = h;
        a2[j] = f2bf(v - bf2f(h));
    }
    uint2 p1, p2;
    p1.x = (unsigned)a1[0] | ((unsigned)a1[1] << 16);
    p1.y = (unsigned)a1[2] | ((unsigned)a1[3] << 16);
    p2.x = (unsigned)a2[0] | ((unsigned)a2[1] << 16);
    p2.y = (unsigned)a2[2] | ((unsigned)a2[3] << 16);
    *(uint2*)(dst + c0)       = p1;
    *(uint2*)(dst + 128 + c0) = p2;
}

// ---------- weight repack into hi/lo-duplicated Wcat [1536][1920] -----------
__global__ __launch_bounds__(256) void repack_w(
    const float* __restrict__ wih, const float* __restrict__ whh, u16* __restrict__ wcat)
{
    int id = blockIdx.x * 256 + threadIdx.x;      // over 1536*1920
    int n = id / KW_, k = id % KW_;
    float w; int lo;
    if (k < 384) {
        int kk = k & 127, grp = k >> 7;           // three 128-groups
        if (kk >= E_) { wcat[id] = 0; return; }
        w = wih[n * E_ + kk];
        lo = (grp == 2);
    } else {
        int kk = (k - 384) & 511, grp = (k - 384) >> 9;
        w = whh[n * H_ + kk];
        lo = (grp == 2);
    }
    u16 h = f2bf(w);
    if (lo) h = f2bf(w - bf2f(h));
    wcat[id] = h;
}

__global__ __launch_bounds__(256) void repack_lin(
    const float* __restrict__ lw, u16* __restrict__ l1, u16* __restrict__ l2)
{
    int i = blockIdx.x * 256 + threadIdx.x;       // over 512*512
    float w = lw[i];
    u16 h = f2bf(w);
    l1[i] = h;
    l2[i] = f2bf(w - bf2f(h));
}

// ---------- one GRU time step, all 3 encoders, fused GEMM + pointwise -------
// Block: 64 batch rows x 64 hidden cols x 3 gates (M=64 doubles B-tile reuse
// vs the 32-row version: B staging traffic halves). Wave w owns cols w*16 of
// each gate for all 64 rows: 4 A-frags + 3 B-frags -> 12 MFMA per ks.
struct BiasPtrs { const float* bih[3]; const float* bhh[3]; };

__global__ __launch_bounds__(256) void gru_step(
    const u16* __restrict__ xs,      // [3][64][1024][256]
    const u16* __restrict__ wcat,    // [3][1536][1920]
    BiasPtrs bp,
    const u16* __restrict__ h1_in, const u16* __restrict__ h2_in,   // [3][1024][512]
    u16* __restrict__ h1_out, u16* __restrict__ h2_out,
    int t)
{
    __shared__ __attribute__((aligned(16))) u16 As[64 * 72];
    __shared__ __attribute__((aligned(16))) u16 Bs[192 * 72];
    const int tid = threadIdx.x;
    const int w = tid >> 6, lane = tid & 63;
    const int l15 = lane & 15, l4 = lane >> 4;
    const int g  = blockIdx.z;
    const int h0 = blockIdx.x * 64;   // x-fastest => XCD-pinned N tile (L2 locality)
    const int r0 = blockIdx.y * 64;

    f32x4 zero = {0.f, 0.f, 0.f, 0.f};
    f32x4 acc_r[4]  = {zero, zero, zero, zero};
    f32x4 acc_z[4]  = {zero, zero, zero, zero};
    f32x4 acc_ni[4] = {zero, zero, zero, zero};
    f32x4 acc_nh[4] = {zero, zero, zero, zero};

    #pragma unroll 1
    for (int c = 0; c < NCH_; ++c) {
        const u16* asrc; int astr;
        if (c < 6) {
            int col = (c < 2) ? c * 64 : (c < 4) ? 128 + (c - 2) * 64 : (c - 4) * 64;
            asrc = xs + (((long)(g * S_ + t)) * B_ + r0) * XW_ + col; astr = XW_;
        } else if (c < 14) { asrc = h1_in + ((long)g * B_ + r0) * H_ + (c - 6) * 64;  astr = H_; }
        else if (c < 22)   { asrc = h2_in + ((long)g * B_ + r0) * H_ + (c - 14) * 64; astr = H_; }
        else               { asrc = h1_in + ((long)g * B_ + r0) * H_ + (c - 22) * 64; astr = H_; }
        #pragma unroll
        for (int i = 0; i < 2; ++i) {
            int s = tid + 256 * i;
            int row = s >> 3, seg = s & 7;
            *(uint4*)(&As[row * 72 + seg * 8]) = *(const uint4*)(asrc + (long)row * astr + seg * 8);
        }
        const u16* bbase = wcat + (long)g * G3_ * KW_ + (long)c * 64;
        #pragma unroll
        for (int i = 0; i < 6; ++i) {
            int s = tid + 256 * i;
            int row = s >> 3, off = (s & 7) * 8;
            int ng = (row >> 6) * H_ + h0 + (row & 63);
            *(uint4*)(&Bs[row * 72 + off]) = *(const uint4*)(bbase + (long)ng * KW_ + off);
        }
        __syncthreads();
        #pragma unroll
        for (int ks = 0; ks < 2; ++ks) {
            short8 br = *(const short8*)(&Bs[(0 * 64 + w * 16 + l15) * 72 + ks * 32 + l4 * 8]);
            short8 bz = *(const short8*)(&Bs[(1 * 64 + w * 16 + l15) * 72 + ks * 32 + l4 * 8]);
            short8 bn = *(const short8*)(&Bs[(2 * 64 + w * 16 + l15) * 72 + ks * 32 + l4 * 8]);
            short8 a0 = *(const short8*)(&As[(0 * 16 + l15) * 72 + ks * 32 + l4 * 8]);
            short8 a1 = *(const short8*)(&As[(1 * 16 + l15) * 72 + ks * 32 + l4 * 8]);
            short8 a2 = *(const short8*)(&As[(2 * 16 + l15) * 72 + ks * 32 + l4 * 8]);
            short8 a3 = *(const short8*)(&As[(3 * 16 + l15) * 72 + ks * 32 + l4 * 8]);
            acc_r[0] = mfma16(a0, br, acc_r[0]);  acc_r[1] = mfma16(a1, br, acc_r[1]);
            acc_r[2] = mfma16(a2, br, acc_r[2]);  acc_r[3] = mfma16(a3, br, acc_r[3]);
            acc_z[0] = mfma16(a0, bz, acc_z[0]);  acc_z[1] = mfma16(a1, bz, acc_z[1]);
            acc_z[2] = mfma16(a2, bz, acc_z[2]);  acc_z[3] = mfma16(a3, bz, acc_z[3]);
            if (c < 6) {
                acc_ni[0] = mfma16(a0, bn, acc_ni[0]); acc_ni[1] = mfma16(a1, bn, acc_ni[1]);
                acc_ni[2] = mfma16(a2, bn, acc_ni[2]); acc_ni[3] = mfma16(a3, bn, acc_ni[3]);
            } else {
                acc_nh[0] = mfma16(a0, bn, acc_nh[0]); acc_nh[1] = mfma16(a1, bn, acc_nh[1]);
                acc_nh[2] = mfma16(a2, bn, acc_nh[2]); acc_nh[3] = mfma16(a3, bn, acc_nh[3]);
            }
        }
        __syncthreads();
    }

    // ---- GRU pointwise epilogue (f32), h reconstructed from bf16 pair ----
    int hc = h0 + w * 16 + l15;
    const float* bih = bp.bih[g];
    const float* bhh = bp.bhh[g];
    float b_ir = bih[hc],          b_hr = bhh[hc];
    float b_iz = bih[H_ + hc],     b_hz = bhh[H_ + hc];
    float b_in = bih[2 * H_ + hc], b_hn = bhh[2 * H_ + hc];
    #pragma unroll
    for (int mt = 0; mt < 4; ++mt) {
        #pragma unroll
        for (int i = 0; i < 4; ++i) {
            int m = r0 + mt * 16 + l4 * 4 + i;
            long idx = ((long)g * B_ + m) * H_ + hc;
            float pr = acc_r[mt][i] + b_ir + b_hr;
            float pz = acc_z[mt][i] + b_iz + b_hz;
            float vi = acc_ni[mt][i] + b_in;
            float vh = acc_nh[mt][i] + b_hn;
            float r = 1.f / (1.f + __expf(-pr));
            float z = 1.f / (1.f + __expf(-pz));
            float n = tanhf(vi + r * vh);
            float hold = bf2f(h1_in[idx]) + bf2f(h2_in[idx]);
            float hnew = (1.f - z) * n + z * hold;
            u16 hh = f2bf(hnew);
            h1_out[idx] = hh;
            h2_out[idx] = f2bf(hnew - bf2f(hh));
        }
    }
}

// ---------- qc = 0.5*(eq+ec) from bf16 pairs, split into bf16 pair ----------
__global__ __launch_bounds__(256) void qc_kernel(
    const u16* __restrict__ h1, const u16* __restrict__ h2,
    u16* __restrict__ q1, u16* __restrict__ q2)
{
    int i = blockIdx.x * 256 + threadIdx.x;       // over 1024*512
    float eq = bf2f(h1[i]) + bf2f(h2[i]);
    float ec = bf2f(h1[B_ * H_ + i]) + bf2f(h2[B_ * H_ + i]);
    float q = 0.5f * (eq + ec);
    u16 h = f2bf(q);
    q1[i] = h;
    q2[i] = f2bf(q - bf2f(h));
}

// ---------- generic NT GEMM with per-chunk source pointers ------------------
struct GArgs { const u16* a[24]; const u16* b[24]; };

__global__ __launch_bounds__(256) void gemm_nt(
    GArgs ga, int nch, int astr, int bstr,
    const float* __restrict__ bias, float* __restrict__ outf,
    u16* __restrict__ ohi, u16* __restrict__ olo, int ldc, int mode)
{
    __shared__ __attribute__((aligned(16))) u16 As[64 * 72];
    __shared__ __attribute__((aligned(16))) u16 Bs[64 * 72];
    const int tid = threadIdx.x;
    const int w = tid >> 6, lane = tid & 63;
    const int l15 = lane & 15, l4 = lane >> 4;
    const int m0 = blockIdx.x * 64, n0 = blockIdx.y * 64;

    f32x4 zero = {0.f, 0.f, 0.f, 0.f};
    f32x4 acc[4] = {zero, zero, zero, zero};

    for (int c = 0; c < nch; ++c) {
        int row = tid >> 2, seg = tid & 3;
        const u16* sa = ga.a[c] + (long)(m0 + row) * astr + seg * 16;
        *(uint4*)(&As[row * 72 + seg * 16])     = *(const uint4*)(sa);
        *(uint4*)(&As[row * 72 + seg * 16 + 8]) = *(const uint4*)(sa + 8);
        const u16* sb = ga.b[c] + (long)(n0 + row) * bstr + seg * 16;
        *(uint4*)(&Bs[row * 72 + seg * 16])     = *(const uint4*)(sb);
        *(uint4*)(&Bs[row * 72 + seg * 16 + 8]) = *(const uint4*)(sb + 8);
        __syncthreads();
        #pragma unroll
        for (int ks = 0; ks < 2; ++ks) {
            short8 bfrag = *(const short8*)(&Bs[(w * 16 + l15) * 72 + ks * 32 + l4 * 8]);
            #pragma unroll
            for (int rt = 0; rt < 4; ++rt) {
                short8 a = *(const short8*)(&As[(rt * 16 + l15) * 72 + ks * 32 + l4 * 8]);
                acc[rt] = mfma16(a, bfrag, acc[rt]);
            }
        }
        __syncthreads();
    }

    int n = n0 + w * 16 + l15;
    float bv = bias ? bias[n] : 0.f;
    #pragma unroll
    for (int rt = 0; rt < 4; ++rt) {
        #pragma unroll
        for (int i = 0; i < 4; ++i) {
            int m = m0 + rt * 16 + l4 * 4 + i;
            float v = acc[rt][i] + bv;
            if (mode == 0) {
                outf[(long)m * ldc + n] = v;
            } else {
                u16 h = f2bf(v);
                ohi[(long)m * ldc + n] = h;
                olo[(long)m * ldc + n] = f2bf(v - bf2f(h));
            }
        }
    }
}

// ---------- row softmax (1024 wide), f32 in/out -----------------------------
__global__ __launch_bounds__(256) void softmax_kernel(
    const float* __restrict__ lg, float* __restrict__ out)
{
    __shared__ float red[256];
    int row = blockIdx.x, tid = threadIdx.x;
    const float* src = lg + (long)row * 1024;
    float x[4];
    float mx = -1e30f;
    #pragma unroll
    for (int i = 0; i < 4; ++i) { x[i] = src[tid + 256 * i]; mx = fmaxf(mx, x[i]); }
    red[tid] = mx; __syncthreads();
    for (int s = 128; s > 0; s >>= 1) { if (tid < s) red[tid] = fmaxf(red[tid], red[tid + s]); __syncthreads(); }
    mx = red[0]; __syncthreads();
    float sm = 0.f;
    #pragma unroll
    for (int i = 0; i < 4; ++i) { x[i] = __expf(x[i] - mx); sm += x[i]; }
    red[tid] = sm; __syncthreads();
    for (int s = 128; s > 0; s >>= 1) { if (tid < s) red[tid] += red[tid + s]; __syncthreads(); }
    float inv = 1.f / red[0];
    float* dst = out + (long)row * 1024;
    #pragma unroll
    for (int i = 0; i < 4; ++i) dst[tid + 256 * i] = x[i] * inv;
}

// ---------------------------------------------------------------------------
extern "C" void kernel_launch(void* const* d_in, const int* in_sizes, int n_in,
                              void* d_out, int out_size, void* d_ws, size_t ws_size,
                              hipStream_t stream)
{
    const int* tok[3] = {(const int*)d_in[0], (const int*)d_in[1], (const int*)d_in[2]};
    const float *emb[3], *wih[3], *whh[3], *bih[3], *bhh[3];
    for (int g = 0; g < 3; ++g) {
        emb[g] = (const float*)d_in[3 + 5 * g];
        wih[g] = (const float*)d_in[4 + 5 * g];
        whh[g] = (const float*)d_in[5 + 5 * g];
        bih[g] = (const float*)d_in[6 + 5 * g];
        bhh[g] = (const float*)d_in[7 + 5 * g];
    }
    const float* lin_w = (const float*)d_in[18];
    const float* lin_b = (const float*)d_in[19];

    char* ws = (char*)d_ws;
    size_t off = 0;
    auto alloc = [&](size_t bytes) { void* p = ws + off; off += (bytes + 255) & ~255ull; return p; };

    const size_t BH  = (size_t)B_ * H_;           // 524288
    const size_t PRB = 3 * BH * 2;                // bf16 plane bytes (3.1 MB)
    const size_t PING = 2 * PRB;                  // h1+h2 per ping

    u16*   Xs   = (u16*)alloc(3ll * S_ * B_ * XW_ * 2);     // 100.7 MB
    u16*   Wcat = (u16*)alloc(3ll * G3_ * KW_ * 2);         // 17.7 MB
    u16*   LW1  = (u16*)alloc((size_t)H_ * H_ * 2);
    u16*   LW2  = (u16*)alloc((size_t)H_ * H_ * 2);
    char*  HB   = (char*)alloc(2 * PING);                   // 12.6 MB
    u16*   QC1  = (u16*)alloc(BH * 2);
    u16*   QC2  = (u16*)alloc(BH * 2);
    u16*   EQ1  = (u16*)alloc(BH * 2);
    u16*   EQ2  = (u16*)alloc(BH * 2);
    float* LG   = (float*)alloc(3ll * B_ * B_ * 4);         // 12.6 MB

    u16* H1[2]; u16* H2[2];
    for (int i = 0; i < 2; ++i) {
        char* pb = HB + (size_t)i * PING;
        H1[i] = (u16*)pb;
        H2[i] = (u16*)(pb + PRB);
    }

    hipMemsetAsync(HB, 0, PING, stream);   // zero h0 (ping 0: both planes)

    for (int g = 0; g < 3; ++g) {
        gather_kernel<<<dim3(S_ * B_ / 8), 256, 0, stream>>>(tok[g], emb[g], Xs + (size_t)g * S_ * B_ * XW_);
        repack_w<<<dim3(G3_ * KW_ / 256), 256, 0, stream>>>(wih[g], whh[g], Wcat + (size_t)g * G3_ * KW_);
    }
    repack_lin<<<dim3(H_ * H_ / 256), 256, 0, stream>>>(lin_w, LW1, LW2);

    BiasPtrs bp;
    for (int g = 0; g < 3; ++g) { bp.bih[g] = bih[g]; bp.bhh[g] = bhh[g]; }

    int p = 0;
    for (int t = S_ - 1; t >= 0; --t) {
        gru_step<<<dim3(8, 16, 3), 256, 0, stream>>>(Xs, Wcat, bp,
            H1[p], H2[p], H1[1 - p], H2[1 - p], t);
        p ^= 1;
    }
    const u16* H1F = H1[p];
    const u16* H2F = H2[p];

    qc_kernel<<<dim3(BH / 256), 256, 0, stream>>>(H1F, H2F, QC1, QC2);

    // eqc = qc @ lin_w.T + lin_b : q1w1 + q2w1 + q1w2 (24 chunks over K=512)
    GArgs ga;
    for (int c = 0; c < 8; ++c)   { ga.a[c] = QC1 + c * 64;        ga.b[c] = LW1 + c * 64; }
    for (int c = 8; c < 16; ++c)  { ga.a[c] = QC2 + (c - 8) * 64;  ga.b[c] = LW1 + (c - 8) * 64; }
    for (int c = 16; c < 24; ++c) { ga.a[c] = QC1 + (c - 16) * 64; ga.b[c] = LW2 + (c - 16) * 64; }
    gemm_nt<<<dim3(16, 8), 256, 0, stream>>>(ga, 24, H_, H_, lin_b, nullptr, EQ1, EQ2, H_, 1);

    // sims: logits = X @ er.T via a1b1 + a2b1 + a1b2
    const u16* R1 = H1F + 2 * BH;
    const u16* R2 = H2F + 2 * BH;
    for (int g = 0; g < 3; ++g) {
        const u16 *A1, *A2;
        if (g == 0)      { A1 = H1F;      A2 = H2F; }
        else if (g == 1) { A1 = H1F + BH; A2 = H2F + BH; }
        else             { A1 = EQ1;      A2 = EQ2; }
        GArgs gs;
        for (int c = 0; c < 8; ++c)   { gs.a[c] = A1 + c * 64;        gs.b[c] = R1 + c * 64; }
        for (int c = 8; c < 16; ++c)  { gs.a[c] = A2 + (c - 8) * 64;  gs.b[c] = R1 + (c - 8) * 64; }
        for (int c = 16; c < 24; ++c) { gs.a[c] = A1 + (c - 16) * 64; gs.b[c] = R2 + (c - 16) * 64; }
        gemm_nt<<<dim3(16, 16), 256, 0, stream>>>(gs, 24, H_, H_, nullptr,
            LG + (size_t)g * B_ * B_, nullptr, nullptr, B_, 0);
    }

    softmax_kernel<<<dim3(3 * B_), 256, 0, stream>>>(LG, (float*)d_out);
}

// Round 5
// 2817.105 us; speedup vs baseline: 1.4762x; 1.3410x over previous
//
#include <hip/hip_runtime.h>

typedef unsigned short u16;
typedef __attribute__((ext_vector_type(8))) short short8;
typedef __attribute__((ext_vector_type(4))) float f32x4;

#define B_   1024
#define S_   64
#define E_   100
#define H_   512
#define G3_  1536
#define XW_  256      /* Xs row: x1[128] | x2[128] */
#define WSZG (32 * 3 * 60 * 512)   /* Wswz elems per encoder = 2,949,120 */
#define GS_  (60 * 512)            /* gate stride inside Wswz */

__device__ __forceinline__ float bf2f(u16 u) {
    union { unsigned int u; float f; } c; c.u = ((unsigned int)u) << 16; return c.f;
}
__device__ __forceinline__ u16 f2bf(float f) {
    union { float f; unsigned int u; } c; c.f = f;
    unsigned int r = c.u + 0x7fffu + ((c.u >> 16) & 1u);
    return (u16)(r >> 16);
}
__device__ __forceinline__ f32x4 mfma16(short8 a, short8 b, f32x4 c) {
    return __builtin_amdgcn_mfma_f32_16x16x32_bf16(a, b, c, 0, 0, 0);
}

// ---------- embedding gather -> bf16 hi/lo pair planes, zero-padded to 128 --
__global__ __launch_bounds__(256) void gather_kernel(
    const int* __restrict__ tok, const float* __restrict__ emb, u16* __restrict__ xs)
{
    int tid = threadIdx.x;
    int hw  = tid & 31;
    int rowid = blockIdx.x * 8 + (tid >> 5);      // rowid = t*1024 + b
    int t = rowid >> 10, b = rowid & 1023;
    int token = tok[b * S_ + t];
    const float* src = emb + (long)token * E_;
    u16* dst = xs + (long)rowid * XW_;
    int c0 = hw * 4;
    u16 a1[4], a2[4];
    #pragma unroll
    for (int j = 0; j < 4; ++j) {
        int c = c0 + j;
        float v = (c < E_) ? src[c] : 0.f;
        u16 h = f2bf(v);
        a1[j] = h;
        a2[j] = f2bf(v - bf2f(h));
    }
    uint2 p1, p2;
    p1.x = (unsigned)a1[0] | ((unsigned)a1[1] << 16);
    p1.y = (unsigned)a1[2] | ((unsigned)a1[3] << 16);
    p2.x = (unsigned)a2[0] | ((unsigned)a2[1] << 16);
    p2.y = (unsigned)a2[2] | ((unsigned)a2[3] << 16);
    *(uint2*)(dst + c0)       = p1;
    *(uint2*)(dst + 128 + c0) = p2;
}

// ---------- weight repack straight into MFMA-fragment order (R3-verified) ---
// Wswz[ht(32)][gate(3)][ks(60)][lane(64)][8] per encoder.
// n = ht*16 + (lane&15), k = ks*32 + (lane>>4)*8 + jj.
// k<384: three 128-col groups of wih (w1,w1,w2); k>=384: three 512-col groups
// of whh (w1,w1,w2).
__global__ __launch_bounds__(256) void repack_swz(
    const float* __restrict__ wih, const float* __restrict__ whh, u16* __restrict__ out)
{
    long idx = (long)blockIdx.x * 256 + threadIdx.x;   // over WSZG
    int jj   = idx & 7;
    int lane = (idx >> 3) & 63;
    int q9   = (int)(idx >> 9);
    int ks   = q9 % 60;
    int q    = q9 / 60;
    int gate = q % 3;
    int ht   = q / 3;
    int n   = ht * 16 + (lane & 15);
    int k   = ks * 32 + (lane >> 4) * 8 + jj;
    int row = gate * H_ + n;
    float w; int lo;
    if (k < 384) {
        int kk = k & 127, grp = k >> 7;
        if (kk >= E_) { out[idx] = 0; return; }
        w = wih[row * E_ + kk];
        lo = (grp == 2);
    } else {
        int kh = k - 384;
        int kk = kh & 511, grp = kh >> 9;
        w = whh[row * H_ + kk];
        lo = (grp == 2);
    }
    u16 h = f2bf(w);
    if (lo) h = f2bf(w - bf2f(h));
    out[idx] = h;
}

__global__ __launch_bounds__(256) void repack_lin(
    const float* __restrict__ lw, u16* __restrict__ l1, u16* __restrict__ l2)
{
    int i = blockIdx.x * 256 + threadIdx.x;       // over 512*512
    float w = lw[i];
    u16 h = f2bf(w);
    l1[i] = h;
    l2[i] = f2bf(w - bf2f(h));
}

// ---------- one GRU time step ------------------------------------------------
// Block: 64 batch x 96 cols (2 ht-tiles x 3 gates). 4 waves = (mh x nh); wave
// tile 32m x 16hc x 3 gates. A (x/h1/h2) staged in LDS once and reused for
// both w1- and w2-fragment sets; B-fragments read directly from the
// fragment-ordered Wswz (contiguous 1KB/wave, L2-resident per XCD).
struct BiasPtrs { const float* bih[3]; const float* bhh[3]; };

__global__ __launch_bounds__(256, 3) void gru_step(
    const u16* __restrict__ xs,      // [3][64][1024][256]
    const u16* __restrict__ wswz,    // [3][WSZG]
    BiasPtrs bp,
    const u16* __restrict__ h1_in, const u16* __restrict__ h2_in,   // [3][1024][512]
    u16* __restrict__ h1_out, u16* __restrict__ h2_out,
    int t)
{
    __shared__ __attribute__((aligned(16))) u16 As[64 * 72];
    const int tid = threadIdx.x;
    const int lane = tid & 63;
    const int mh = tid >> 7;          // 0,1
    const int nh = (tid >> 6) & 1;    // 0,1
    const int l15 = lane & 15, l4 = lane >> 4;
    const int htp = blockIdx.x;       // 0..15  (x-fastest => XCD-pinned B slice)
    const int m0  = blockIdx.y * 64;
    const int g   = blockIdx.z;
    const int ht  = htp * 2 + nh;

    const u16* wg  = wswz + (long)g * WSZG + (long)ht * (3 * GS_) + lane * 8;
    const u16* xb  = xs + ((long)(g * S_ + t) * B_ + m0) * XW_;
    const u16* hb1 = h1_in + ((long)g * B_ + m0) * H_;
    const u16* hb2 = h2_in + ((long)g * B_ + m0) * H_;

    f32x4 zero = {0.f, 0.f, 0.f, 0.f};
    f32x4 acc_r[2]  = {zero, zero};
    f32x4 acc_z[2]  = {zero, zero};
    f32x4 acc_ni[2] = {zero, zero};
    f32x4 acc_nh[2] = {zero, zero};

    const int arow = mh * 32 + l15;

    // ---- phase X1 (dual: w1 ks=2j+ksl, w2 ks=8+2j+ksl), n-gate -> ni ----
    #pragma unroll 1
    for (int j = 0; j < 2; ++j) {
        #pragma unroll
        for (int i = 0; i < 2; ++i) {
            int s = tid + 256 * i; int row = s >> 3, seg = s & 7;
            *(uint4*)(&As[row * 72 + seg * 8]) =
                *(const uint4*)(xb + (long)row * XW_ + j * 64 + seg * 8);
        }
        __syncthreads();
        #pragma unroll
        for (int ksl = 0; ksl < 2; ++ksl) {
            int k1 = (2 * j + ksl) * 512, k2 = (8 + 2 * j + ksl) * 512;
            short8 br1 = *(const short8*)(wg + k1);
            short8 bz1 = *(const short8*)(wg + GS_ + k1);
            short8 bn1 = *(const short8*)(wg + 2 * GS_ + k1);
            short8 br2 = *(const short8*)(wg + k2);
            short8 bz2 = *(const short8*)(wg + GS_ + k2);
            short8 bn2 = *(const short8*)(wg + 2 * GS_ + k2);
            short8 a0 = *(const short8*)(&As[arow * 72 + ksl * 32 + l4 * 8]);
            short8 a1 = *(const short8*)(&As[(arow + 16) * 72 + ksl * 32 + l4 * 8]);
            acc_r[0]  = mfma16(a0, br1, acc_r[0]);  acc_r[1]  = mfma16(a1, br1, acc_r[1]);
            acc_z[0]  = mfma16(a0, bz1, acc_z[0]);  acc_z[1]  = mfma16(a1, bz1, acc_z[1]);
            acc_ni[0] = mfma16(a0, bn1, acc_ni[0]); acc_ni[1] = mfma16(a1, bn1, acc_ni[1]);
            acc_r[0]  = mfma16(a0, br2, acc_r[0]);  acc_r[1]  = mfma16(a1, br2, acc_r[1]);
            acc_z[0]  = mfma16(a0, bz2, acc_z[0]);  acc_z[1]  = mfma16(a1, bz2, acc_z[1]);
            acc_ni[0] = mfma16(a0, bn2, acc_ni[0]); acc_ni[1] = mfma16(a1, bn2, acc_ni[1]);
        }
        __syncthreads();
    }
    // ---- phase X2 (single: w1 ks=4+2j+ksl), n-gate -> ni ----
    #pragma unroll 1
    for (int j = 0; j < 2; ++j) {
        #pragma unroll
        for (int i = 0; i < 2; ++i) {
            int s = tid + 256 * i; int row = s >> 3, seg = s & 7;
            *(uint4*)(&As[row * 72 + seg * 8]) =
                *(const uint4*)(xb + (long)row * XW_ + 128 + j * 64 + seg * 8);
        }
        __syncthreads();
        #pragma unroll
        for (int ksl = 0; ksl < 2; ++ksl) {
            int k1 = (4 + 2 * j + ksl) * 512;
            short8 br1 = *(const short8*)(wg + k1);
            short8 bz1 = *(const short8*)(wg + GS_ + k1);
            short8 bn1 = *(const short8*)(wg + 2 * GS_ + k1);
            short8 a0 = *(const short8*)(&As[arow * 72 + ksl * 32 + l4 * 8]);
            short8 a1 = *(const short8*)(&As[(arow + 16) * 72 + ksl * 32 + l4 * 8]);
            acc_r[0]  = mfma16(a0, br1, acc_r[0]);  acc_r[1]  = mfma16(a1, br1, acc_r[1]);
            acc_z[0]  = mfma16(a0, bz1, acc_z[0]);  acc_z[1]  = mfma16(a1, bz1, acc_z[1]);
            acc_ni[0] = mfma16(a0, bn1, acc_ni[0]); acc_ni[1] = mfma16(a1, bn1, acc_ni[1]);
        }
        __syncthreads();
    }
    // ---- phase H1 (dual: w1 ks=12+2j+ksl, w2 ks=44+2j+ksl), n-gate -> nh ----
    #pragma unroll 1
    for (int j = 0; j < 8; ++j) {
        #pragma unroll
        for (int i = 0; i < 2; ++i) {
            int s = tid + 256 * i; int row = s >> 3, seg = s & 7;
            *(uint4*)(&As[row * 72 + seg * 8]) =
                *(const uint4*)(hb1 + (long)row * H_ + j * 64 + seg * 8);
        }
        __syncthreads();
        #pragma unroll
        for (int ksl = 0; ksl < 2; ++ksl) {
            int k1 = (12 + 2 * j + ksl) * 512, k2 = (44 + 2 * j + ksl) * 512;
            short8 br1 = *(const short8*)(wg + k1);
            short8 bz1 = *(const short8*)(wg + GS_ + k1);
            short8 bn1 = *(const short8*)(wg + 2 * GS_ + k1);
            short8 br2 = *(const short8*)(wg + k2);
            short8 bz2 = *(const short8*)(wg + GS_ + k2);
            short8 bn2 = *(const short8*)(wg + 2 * GS_ + k2);
            short8 a0 = *(const short8*)(&As[arow * 72 + ksl * 32 + l4 * 8]);
            short8 a1 = *(const short8*)(&As[(arow + 16) * 72 + ksl * 32 + l4 * 8]);
            acc_r[0]  = mfma16(a0, br1, acc_r[0]);  acc_r[1]  = mfma16(a1, br1, acc_r[1]);
            acc_z[0]  = mfma16(a0, bz1, acc_z[0]);  acc_z[1]  = mfma16(a1, bz1, acc_z[1]);
            acc_nh[0] = mfma16(a0, bn1, acc_nh[0]); acc_nh[1] = mfma16(a1, bn1, acc_nh[1]);
            acc_r[0]  = mfma16(a0, br2, acc_r[0]);  acc_r[1]  = mfma16(a1, br2, acc_r[1]);
            acc_z[0]  = mfma16(a0, bz2, acc_z[0]);  acc_z[1]  = mfma16(a1, bz2, acc_z[1]);
            acc_nh[0] = mfma16(a0, bn2, acc_nh[0]); acc_nh[1] = mfma16(a1, bn2, acc_nh[1]);
        }
        __syncthreads();
    }
    // ---- phase H2 (single: w1 ks=28+2j+ksl), n-gate -> nh ----
    #pragma unroll 1
    for (int j = 0; j < 8; ++j) {
        #pragma unroll
        for (int i = 0; i < 2; ++i) {
            int s = tid + 256 * i; int row = s >> 3, seg = s & 7;
            *(uint4*)(&As[row * 72 + seg * 8]) =
                *(const uint4*)(hb2 + (long)row * H_ + j * 64 + seg * 8);
        }
        __syncthreads();
        #pragma unroll
        for (int ksl = 0; ksl < 2; ++ksl) {
            int k1 = (28 + 2 * j + ksl) * 512;
            short8 br1 = *(const short8*)(wg + k1);
            short8 bz1 = *(const short8*)(wg + GS_ + k1);
            short8 bn1 = *(const short8*)(wg + 2 * GS_ + k1);
            short8 a0 = *(const short8*)(&As[arow * 72 + ksl * 32 + l4 * 8]);
            short8 a1 = *(const short8*)(&As[(arow + 16) * 72 + ksl * 32 + l4 * 8]);
            acc_r[0]  = mfma16(a0, br1, acc_r[0]);  acc_r[1]  = mfma16(a1, br1, acc_r[1]);
            acc_z[0]  = mfma16(a0, bz1, acc_z[0]);  acc_z[1]  = mfma16(a1, bz1, acc_z[1]);
            acc_nh[0] = mfma16(a0, bn1, acc_nh[0]); acc_nh[1] = mfma16(a1, bn1, acc_nh[1]);
        }
        __syncthreads();
    }

    // ---- GRU pointwise epilogue (f32), h reconstructed from bf16 pair ----
    int hc = ht * 16 + l15;
    const float* bih = bp.bih[g];
    const float* bhh = bp.bhh[g];
    float b_ir = bih[hc],          b_hr = bhh[hc];
    float b_iz = bih[H_ + hc],     b_hz = bhh[H_ + hc];
    float b_in = bih[2 * H_ + hc], b_hn = bhh[2 * H_ + hc];
    #pragma unroll
    for (int mt = 0; mt < 2; ++mt) {
        #pragma unroll
        for (int i = 0; i < 4; ++i) {
            int m = m0 + mh * 32 + mt * 16 + l4 * 4 + i;
            long idx = ((long)g * B_ + m) * H_ + hc;
            float pr = acc_r[mt][i] + b_ir + b_hr;
            float pz = acc_z[mt][i] + b_iz + b_hz;
            float vi = acc_ni[mt][i] + b_in;
            float vh = acc_nh[mt][i] + b_hn;
            float r = 1.f / (1.f + __expf(-pr));
            float z = 1.f / (1.f + __expf(-pz));
            float n = tanhf(vi + r * vh);
            float hold = bf2f(h1_in[idx]) + bf2f(h2_in[idx]);
            float hnew = (1.f - z) * n + z * hold;
            u16 hh = f2bf(hnew);
            h1_out[idx] = hh;
            h2_out[idx] = f2bf(hnew - bf2f(hh));
        }
    }
}

// ---------- qc = 0.5*(eq+ec) from bf16 pairs, split into bf16 pair ----------
__global__ __launch_bounds__(256) void qc_kernel(
    const u16* __restrict__ h1, const u16* __restrict__ h2,
    u16* __restrict__ q1, u16* __restrict__ q2)
{
    int i = blockIdx.x * 256 + threadIdx.x;       // over 1024*512
    float eq = bf2f(h1[i]) + bf2f(h2[i]);
    float ec = bf2f(h1[B_ * H_ + i]) + bf2f(h2[B_ * H_ + i]);
    float q = 0.5f * (eq + ec);
    u16 h = f2bf(q);
    q1[i] = h;
    q2[i] = f2bf(q - bf2f(h));
}

// ---------- generic NT GEMM with per-chunk source pointers ------------------
struct GArgs { const u16* a[24]; const u16* b[24]; };

__global__ __launch_bounds__(256) void gemm_nt(
    GArgs ga, int nch, int astr, int bstr,
    const float* __restrict__ bias, float* __restrict__ outf,
    u16* __restrict__ ohi, u16* __restrict__ olo, int ldc, int mode)
{
    __shared__ __attribute__((aligned(16))) u16 As[64 * 72];
    __shared__ __attribute__((aligned(16))) u16 Bs[64 * 72];
    const int tid = threadIdx.x;
    const int w = tid >> 6, lane = tid & 63;
    const int l15 = lane & 15, l4 = lane >> 4;
    const int m0 = blockIdx.x * 64, n0 = blockIdx.y * 64;

    f32x4 zero = {0.f, 0.f, 0.f, 0.f};
    f32x4 acc[4] = {zero, zero, zero, zero};

    for (int c = 0; c < nch; ++c) {
        int row = tid >> 2, seg = tid & 3;
        const u16* sa = ga.a[c] + (long)(m0 + row) * astr + seg * 16;
        *(uint4*)(&As[row * 72 + seg * 16])     = *(const uint4*)(sa);
        *(uint4*)(&As[row * 72 + seg * 16 + 8]) = *(const uint4*)(sa + 8);
        const u16* sb = ga.b[c] + (long)(n0 + row) * bstr + seg * 16;
        *(uint4*)(&Bs[row * 72 + seg * 16])     = *(const uint4*)(sb);
        *(uint4*)(&Bs[row * 72 + seg * 16 + 8]) = *(const uint4*)(sb + 8);
        __syncthreads();
        #pragma unroll
        for (int ks = 0; ks < 2; ++ks) {
            short8 bfrag = *(const short8*)(&Bs[(w * 16 + l15) * 72 + ks * 32 + l4 * 8]);
            #pragma unroll
            for (int rt = 0; rt < 4; ++rt) {
                short8 a = *(const short8*)(&As[(rt * 16 + l15) * 72 + ks * 32 + l4 * 8]);
                acc[rt] = mfma16(a, bfrag, acc[rt]);
            }
        }
        __syncthreads();
    }

    int n = n0 + w * 16 + l15;
    float bv = bias ? bias[n] : 0.f;
    #pragma unroll
    for (int rt = 0; rt < 4; ++rt) {
        #pragma unroll
        for (int i = 0; i < 4; ++i) {
            int m = m0 + rt * 16 + l4 * 4 + i;
            float v = acc[rt][i] + bv;
            if (mode == 0) {
                outf[(long)m * ldc + n] = v;
            } else {
                u16 h = f2bf(v);
                ohi[(long)m * ldc + n] = h;
                olo[(long)m * ldc + n] = f2bf(v - bf2f(h));
            }
        }
    }
}

// ---------- row softmax (1024 wide), f32 in/out -----------------------------
__global__ __launch_bounds__(256) void softmax_kernel(
    const float* __restrict__ lg, float* __restrict__ out)
{
    __shared__ float red[256];
    int row = blockIdx.x, tid = threadIdx.x;
    const float* src = lg + (long)row * 1024;
    float x[4];
    float mx = -1e30f;
    #pragma unroll
    for (int i = 0; i < 4; ++i) { x[i] = src[tid + 256 * i]; mx = fmaxf(mx, x[i]); }
    red[tid] = mx; __syncthreads();
    for (int s = 128; s > 0; s >>= 1) { if (tid < s) red[tid] = fmaxf(red[tid], red[tid + s]); __syncthreads(); }
    mx = red[0]; __syncthreads();
    float sm = 0.f;
    #pragma unroll
    for (int i = 0; i < 4; ++i) { x[i] = __expf(x[i] - mx); sm += x[i]; }
    red[tid] = sm; __syncthreads();
    for (int s = 128; s > 0; s >>= 1) { if (tid < s) red[tid] += red[tid + s]; __syncthreads(); }
    float inv = 1.f / red[0];
    float* dst = out + (long)row * 1024;
    #pragma unroll
    for (int i = 0; i < 4; ++i) dst[tid + 256 * i] = x[i] * inv;
}

// ---------------------------------------------------------------------------
extern "C" void kernel_launch(void* const* d_in, const int* in_sizes, int n_in,
                              void* d_out, int out_size, void* d_ws, size_t ws_size,
                              hipStream_t stream)
{
    const int* tok[3] = {(const int*)d_in[0], (const int*)d_in[1], (const int*)d_in[2]};
    const float *emb[3], *wih[3], *whh[3], *bih[3], *bhh[3];
    for (int g = 0; g < 3; ++g) {
        emb[g] = (const float*)d_in[3 + 5 * g];
        wih[g] = (const float*)d_in[4 + 5 * g];
        whh[g] = (const float*)d_in[5 + 5 * g];
        bih[g] = (const float*)d_in[6 + 5 * g];
        bhh[g] = (const float*)d_in[7 + 5 * g];
    }
    const float* lin_w = (const float*)d_in[18];
    const float* lin_b = (const float*)d_in[19];

    char* ws = (char*)d_ws;
    size_t off = 0;
    auto alloc = [&](size_t bytes) { void* p = ws + off; off += (bytes + 255) & ~255ull; return p; };

    const size_t BH  = (size_t)B_ * H_;           // 524288
    const size_t PRB = 3 * BH * 2;                // bf16 plane bytes (3.1 MB)
    const size_t PING = 2 * PRB;                  // h1+h2 per ping

    u16*   Xs   = (u16*)alloc(3ll * S_ * B_ * XW_ * 2);     // 100.7 MB
    u16*   Wswz = (u16*)alloc(3ll * WSZG * 2);              // 17.7 MB
    u16*   LW1  = (u16*)alloc((size_t)H_ * H_ * 2);
    u16*   LW2  = (u16*)alloc((size_t)H_ * H_ * 2);
    char*  HB   = (char*)alloc(2 * PING);                   // 12.6 MB
    u16*   QC1  = (u16*)alloc(BH * 2);
    u16*   QC2  = (u16*)alloc(BH * 2);
    u16*   EQ1  = (u16*)alloc(BH * 2);
    u16*   EQ2  = (u16*)alloc(BH * 2);
    float* LG   = (float*)alloc(3ll * B_ * B_ * 4);         // 12.6 MB

    u16* H1[2]; u16* H2[2];
    for (int i = 0; i < 2; ++i) {
        char* pb = HB + (size_t)i * PING;
        H1[i] = (u16*)pb;
        H2[i] = (u16*)(pb + PRB);
    }

    hipMemsetAsync(HB, 0, PING, stream);   // zero h0 (ping 0: both planes)

    for (int g = 0; g < 3; ++g) {
        gather_kernel<<<dim3(S_ * B_ / 8), 256, 0, stream>>>(tok[g], emb[g], Xs + (size_t)g * S_ * B_ * XW_);
        repack_swz<<<dim3(WSZG / 256), 256, 0, stream>>>(wih[g], whh[g], Wswz + (size_t)g * WSZG);
    }
    repack_lin<<<dim3(H_ * H_ / 256), 256, 0, stream>>>(lin_w, LW1, LW2);

    BiasPtrs bp;
    for (int g = 0; g < 3; ++g) { bp.bih[g] = bih[g]; bp.bhh[g] = bhh[g]; }

    int p = 0;
    for (int t = S_ - 1; t >= 0; --t) {
        gru_step<<<dim3(16, 16, 3), 256, 0, stream>>>(Xs, Wswz, bp,
            H1[p], H2[p], H1[1 - p], H2[1 - p], t);
        p ^= 1;
    }
    const u16* H1F = H1[p];
    const u16* H2F = H2[p];

    qc_kernel<<<dim3(BH / 256), 256, 0, stream>>>(H1F, H2F, QC1, QC2);

    // eqc = qc @ lin_w.T + lin_b : q1w1 + q2w1 + q1w2 (24 chunks over K=512)
    GArgs ga;
    for (int c = 0; c < 8; ++c)   { ga.a[c] = QC1 + c * 64;        ga.b[c] = LW1 + c * 64; }
    for (int c = 8; c < 16; ++c)  { ga.a[c] = QC2 + (c - 8) * 64;  ga.b[c] = LW1 + (c - 8) * 64; }
    for (int c = 16; c < 24; ++c) { ga.a[c] = QC1 + (c - 16) * 64; ga.b[c] = LW2 + (c - 16) * 64; }
    gemm_nt<<<dim3(16, 8), 256, 0, stream>>>(ga, 24, H_, H_, lin_b, nullptr, EQ1, EQ2, H_, 1);

    // sims: logits = X @ er.T via a1b1 + a2b1 + a1b2
    const u16* R1 = H1F + 2 * BH;
    const u16* R2 = H2F + 2 * BH;
    for (int g = 0; g < 3; ++g) {
        const u16 *A1, *A2;
        if (g == 0)      { A1 = H1F;      A2 = H2F; }
        else if (g == 1) { A1 = H1F + BH; A2 = H2F + BH; }
        else             { A1 = EQ1;      A2 = EQ2; }
        GArgs gs;
        for (int c = 0; c < 8; ++c)   { gs.a[c] = A1 + c * 64;        gs.b[c] = R1 + c * 64; }
        for (int c = 8; c < 16; ++c)  { gs.a[c] = A2 + (c - 8) * 64;  gs.b[c] = R1 + (c - 8) * 64; }
        for (int c = 16; c < 24; ++c) { gs.a[c] = A1 + (c - 16) * 64; gs.b[c] = R2 + (c - 16) * 64; }
        gemm_nt<<<dim3(16, 16), 256, 0, stream>>>(gs, 24, H_, H_, nullptr,
            LG + (size_t)g * B_ * B_, nullptr, nullptr, B_, 0);
    }

    softmax_kernel<<<dim3(3 * B_), 256, 0, stream>>>(LG, (float*)d_out);
}

// Round 6
// 2313.055 us; speedup vs baseline: 1.7979x; 1.2179x over previous
//
#include <hip/hip_runtime.h>

typedef unsigned short u16;
typedef __attribute__((ext_vector_type(8))) short short8;
typedef __attribute__((ext_vector_type(4))) float f32x4;

#define B_   1024
#define S_   64
#define E_   100
#define H_   512
#define G3_  1536
#define XW_  256      /* Xs row: x1[128] | x2[128] */
#define WSZG (32 * 3 * 60 * 512)   /* Wswz elems per encoder = 2,949,120 */
#define GS_  (60 * 512)            /* gate stride inside Wswz */

__device__ __forceinline__ float bf2f(u16 u) {
    union { unsigned int u; float f; } c; c.u = ((unsigned int)u) << 16; return c.f;
}
__device__ __forceinline__ u16 f2bf(float f) {
    union { float f; unsigned int u; } c; c.f = f;
    unsigned int r = c.u + 0x7fffu + ((c.u >> 16) & 1u);
    return (u16)(r >> 16);
}
__device__ __forceinline__ f32x4 mfma16(short8 a, short8 b, f32x4 c) {
    return __builtin_amdgcn_mfma_f32_16x16x32_bf16(a, b, c, 0, 0, 0);
}

// ---------- embedding gather -> bf16 hi/lo pair planes, zero-padded to 128 --
__global__ __launch_bounds__(256) void gather_kernel(
    const int* __restrict__ tok, const float* __restrict__ emb, u16* __restrict__ xs)
{
    int tid = threadIdx.x;
    int hw  = tid & 31;
    int rowid = blockIdx.x * 8 + (tid >> 5);      // rowid = t*1024 + b
    int t = rowid >> 10, b = rowid & 1023;
    int token = tok[b * S_ + t];
    const float* src = emb + (long)token * E_;
    u16* dst = xs + (long)rowid * XW_;
    int c0 = hw * 4;
    u16 a1[4], a2[4];
    #pragma unroll
    for (int j = 0; j < 4; ++j) {
        int c = c0 + j;
        float v = (c < E_) ? src[c] : 0.f;
        u16 h = f2bf(v);
        a1[j] = h;
        a2[j] = f2bf(v - bf2f(h));
    }
    uint2 p1, p2;
    p1.x = (unsigned)a1[0] | ((unsigned)a1[1] << 16);
    p1.y = (unsigned)a1[2] | ((unsigned)a1[3] << 16);
    p2.x = (unsigned)a2[0] | ((unsigned)a2[1] << 16);
    p2.y = (unsigned)a2[2] | ((unsigned)a2[3] << 16);
    *(uint2*)(dst + c0)       = p1;
    *(uint2*)(dst + 128 + c0) = p2;
}

// ---------- weight repack straight into MFMA-fragment order (R3-verified) ---
// Wswz[ht(32)][gate(3)][ks(60)][lane(64)][8] per encoder.
// n = ht*16 + (lane&15), k = ks*32 + (lane>>4)*8 + jj.
// k<384: three 128-col groups of wih (w1,w1,w2); k>=384: three 512-col groups
// of whh (w1,w1,w2).
__global__ __launch_bounds__(256) void repack_swz(
    const float* __restrict__ wih, const float* __restrict__ whh, u16* __restrict__ out)
{
    long idx = (long)blockIdx.x * 256 + threadIdx.x;   // over WSZG
    int jj   = idx & 7;
    int lane = (idx >> 3) & 63;
    int q9   = (int)(idx >> 9);
    int ks   = q9 % 60;
    int q    = q9 / 60;
    int gate = q % 3;
    int ht   = q / 3;
    int n   = ht * 16 + (lane & 15);
    int k   = ks * 32 + (lane >> 4) * 8 + jj;
    int row = gate * H_ + n;
    float w; int lo;
    if (k < 384) {
        int kk = k & 127, grp = k >> 7;
        if (kk >= E_) { out[idx] = 0; return; }
        w = wih[row * E_ + kk];
        lo = (grp == 2);
    } else {
        int kh = k - 384;
        int kk = kh & 511, grp = kh >> 9;
        w = whh[row * H_ + kk];
        lo = (grp == 2);
    }
    u16 h = f2bf(w);
    if (lo) h = f2bf(w - bf2f(h));
    out[idx] = h;
}

__global__ __launch_bounds__(256) void repack_lin(
    const float* __restrict__ lw, u16* __restrict__ l1, u16* __restrict__ l2)
{
    int i = blockIdx.x * 256 + threadIdx.x;       // over 512*512
    float w = lw[i];
    u16 h = f2bf(w);
    l1[i] = h;
    l2[i] = f2bf(w - bf2f(h));
}

// ---------- one GRU time step ------------------------------------------------
// Block: 64 batch x 64 cols (2 ht x 3 gates in fragment space). 4 waves =
// (kh x nh): kh = K-half, nh = ht. Each wave: full 64m x 16hc x 3 gates over
// half of K -> every 1KB B-fragment feeds 4 MFMAs (2x the R5 reuse).
// Disjoint K-halves use disjoint A-chunks: stage 2 chunks/super-iter into a
// 2-slot LDS buffer (half the barriers). Partials combined via LDS reduction.
struct BiasPtrs { const float* bih[3]; const float* bhh[3]; };

__global__ __launch_bounds__(256, 3) void gru_step(
    const u16* __restrict__ xs,      // [3][64][1024][256]
    const u16* __restrict__ wswz,    // [3][WSZG]
    BiasPtrs bp,
    const u16* __restrict__ h1_in, const u16* __restrict__ h2_in,   // [3][1024][512]
    u16* __restrict__ h1_out, u16* __restrict__ h2_out,
    int t)
{
    __shared__ __attribute__((aligned(16))) u16 As[2 * 64 * 72];
    const int tid = threadIdx.x;
    const int lane = tid & 63;
    const int kh = tid >> 7;          // K-half  (0,1)
    const int nh = (tid >> 6) & 1;    // ht      (0,1)
    const int l15 = lane & 15, l4 = lane >> 4;
    const int htp = blockIdx.x;       // 0..15  (x-fastest => XCD-pinned B slice)
    const int m0  = blockIdx.y * 64;
    const int g   = blockIdx.z;
    const int ht  = htp * 2 + nh;

    const u16* wg  = wswz + (long)g * WSZG + (long)ht * (3 * GS_) + lane * 8;
    const u16* xb  = xs + ((long)(g * S_ + t) * B_ + m0) * XW_;
    const u16* hb1 = h1_in + ((long)g * B_ + m0) * H_;
    const u16* hb2 = h2_in + ((long)g * B_ + m0) * H_;
    u16* slotp = As + kh * (64 * 72);

    f32x4 zero = {0.f, 0.f, 0.f, 0.f};
    f32x4 acc_r[4]  = {zero, zero, zero, zero};
    f32x4 acc_z[4]  = {zero, zero, zero, zero};
    f32x4 acc_ni[4] = {zero, zero, zero, zero};
    f32x4 acc_nh[4] = {zero, zero, zero, zero};

    auto stage2 = [&](const u16* s0, const u16* s1, int stride) {
        #pragma unroll
        for (int i = 0; i < 2; ++i) {
            int s = tid + 256 * i;
            int row = s >> 3, seg = s & 7;
            *(uint4*)(&As[row * 72 + seg * 8]) =
                *(const uint4*)(s0 + (long)row * stride + seg * 8);
            *(uint4*)(&As[64 * 72 + row * 72 + seg * 8]) =
                *(const uint4*)(s1 + (long)row * stride + seg * 8);
        }
    };
    auto consume_dual = [&](const u16* b1, const u16* b2, f32x4* accn) {
        #pragma unroll
        for (int ksl = 0; ksl < 2; ++ksl) {
            short8 br1 = *(const short8*)(b1 + ksl * 512);
            short8 bz1 = *(const short8*)(b1 + GS_ + ksl * 512);
            short8 bn1 = *(const short8*)(b1 + 2 * GS_ + ksl * 512);
            short8 br2 = *(const short8*)(b2 + ksl * 512);
            short8 bz2 = *(const short8*)(b2 + GS_ + ksl * 512);
            short8 bn2 = *(const short8*)(b2 + 2 * GS_ + ksl * 512);
            short8 a[4];
            #pragma unroll
            for (int q = 0; q < 4; ++q)
                a[q] = *(const short8*)(&slotp[(q * 16 + l15) * 72 + ksl * 32 + l4 * 8]);
            #pragma unroll
            for (int q = 0; q < 4; ++q) {
                acc_r[q] = mfma16(a[q], br1, acc_r[q]);
                acc_z[q] = mfma16(a[q], bz1, acc_z[q]);
                accn[q]  = mfma16(a[q], bn1, accn[q]);
                acc_r[q] = mfma16(a[q], br2, acc_r[q]);
                acc_z[q] = mfma16(a[q], bz2, acc_z[q]);
                accn[q]  = mfma16(a[q], bn2, accn[q]);
            }
        }
    };
    auto consume_single = [&](const u16* b1, f32x4* accn) {
        #pragma unroll
        for (int ksl = 0; ksl < 2; ++ksl) {
            short8 br1 = *(const short8*)(b1 + ksl * 512);
            short8 bz1 = *(const short8*)(b1 + GS_ + ksl * 512);
            short8 bn1 = *(const short8*)(b1 + 2 * GS_ + ksl * 512);
            short8 a[4];
            #pragma unroll
            for (int q = 0; q < 4; ++q)
                a[q] = *(const short8*)(&slotp[(q * 16 + l15) * 72 + ksl * 32 + l4 * 8]);
            #pragma unroll
            for (int q = 0; q < 4; ++q) {
                acc_r[q] = mfma16(a[q], br1, acc_r[q]);
                acc_z[q] = mfma16(a[q], bz1, acc_z[q]);
                accn[q]  = mfma16(a[q], bn1, accn[q]);
            }
        }
    };

    // X1: slot kh holds x cols kh*64; dual B ks = (2kh+ksl) and (8+2kh+ksl)
    stage2(xb, xb + 64, XW_);
    __syncthreads();
    consume_dual(wg + (2 * kh) * 512, wg + (8 + 2 * kh) * 512, acc_ni);
    __syncthreads();
    // X2: x cols 128 + kh*64; single B ks = 4+2kh+ksl
    stage2(xb + 128, xb + 192, XW_);
    __syncthreads();
    consume_single(wg + (4 + 2 * kh) * 512, acc_ni);
    __syncthreads();
    // H1: slot kh holds h1 chunk (4kh+i); dual ks = 12+8kh+2i+ksl and +32
    #pragma unroll 1
    for (int i = 0; i < 4; ++i) {
        stage2(hb1 + i * 64, hb1 + (i + 4) * 64, H_);
        __syncthreads();
        consume_dual(wg + (12 + 8 * kh + 2 * i) * 512,
                     wg + (44 + 8 * kh + 2 * i) * 512, acc_nh);
        __syncthreads();
    }
    // H2: single ks = 28+8kh+2i+ksl
    #pragma unroll 1
    for (int i = 0; i < 4; ++i) {
        stage2(hb2 + i * 64, hb2 + (i + 4) * 64, H_);
        __syncthreads();
        consume_single(wg + (28 + 8 * kh + 2 * i) * 512, acc_nh);
        __syncthreads();
    }

    // ---- K-half reduction through LDS (2 rounds, 16 KB each) ----
    f32x4* rp = (f32x4*)As;
    const int ridx = (nh * 64 + lane) * 8;
    if (kh == 1) {
        #pragma unroll
        for (int q = 0; q < 4; ++q) { rp[ridx + q] = acc_r[q]; rp[ridx + 4 + q] = acc_z[q]; }
    }
    __syncthreads();
    if (kh == 0) {
        #pragma unroll
        for (int q = 0; q < 4; ++q) { acc_r[q] += rp[ridx + q]; acc_z[q] += rp[ridx + 4 + q]; }
    }
    __syncthreads();
    if (kh == 1) {
        #pragma unroll
        for (int q = 0; q < 4; ++q) { rp[ridx + q] = acc_ni[q]; rp[ridx + 4 + q] = acc_nh[q]; }
    }
    __syncthreads();
    if (kh == 0) {
        #pragma unroll
        for (int q = 0; q < 4; ++q) { acc_ni[q] += rp[ridx + q]; acc_nh[q] += rp[ridx + 4 + q]; }

        // ---- GRU pointwise epilogue (f32), h reconstructed from bf16 pair --
        int hc = ht * 16 + l15;
        const float* bih = bp.bih[g];
        const float* bhh = bp.bhh[g];
        float b_ir = bih[hc],          b_hr = bhh[hc];
        float b_iz = bih[H_ + hc],     b_hz = bhh[H_ + hc];
        float b_in = bih[2 * H_ + hc], b_hn = bhh[2 * H_ + hc];
        #pragma unroll
        for (int mt = 0; mt < 4; ++mt) {
            #pragma unroll
            for (int i = 0; i < 4; ++i) {
                int m = m0 + mt * 16 + l4 * 4 + i;
                long idx = ((long)g * B_ + m) * H_ + hc;
                float pr = acc_r[mt][i] + b_ir + b_hr;
                float pz = acc_z[mt][i] + b_iz + b_hz;
                float vi = acc_ni[mt][i] + b_in;
                float vh = acc_nh[mt][i] + b_hn;
                float r = 1.f / (1.f + __expf(-pr));
                float z = 1.f / (1.f + __expf(-pz));
                float n = tanhf(vi + r * vh);
                float hold = bf2f(h1_in[idx]) + bf2f(h2_in[idx]);
                float hnew = (1.f - z) * n + z * hold;
                u16 hh = f2bf(hnew);
                h1_out[idx] = hh;
                h2_out[idx] = f2bf(hnew - bf2f(hh));
            }
        }
    }
}

// ---------- qc = 0.5*(eq+ec) from bf16 pairs, split into bf16 pair ----------
__global__ __launch_bounds__(256) void qc_kernel(
    const u16* __restrict__ h1, const u16* __restrict__ h2,
    u16* __restrict__ q1, u16* __restrict__ q2)
{
    int i = blockIdx.x * 256 + threadIdx.x;       // over 1024*512
    float eq = bf2f(h1[i]) + bf2f(h2[i]);
    float ec = bf2f(h1[B_ * H_ + i]) + bf2f(h2[B_ * H_ + i]);
    float q = 0.5f * (eq + ec);
    u16 h = f2bf(q);
    q1[i] = h;
    q2[i] = f2bf(q - bf2f(h));
}

// ---------- generic NT GEMM with per-chunk source pointers ------------------
struct GArgs { const u16* a[24]; const u16* b[24]; };

__global__ __launch_bounds__(256) void gemm_nt(
    GArgs ga, int nch, int astr, int bstr,
    const float* __restrict__ bias, float* __restrict__ outf,
    u16* __restrict__ ohi, u16* __restrict__ olo, int ldc, int mode)
{
    __shared__ __attribute__((aligned(16))) u16 As[64 * 72];
    __shared__ __attribute__((aligned(16))) u16 Bs[64 * 72];
    const int tid = threadIdx.x;
    const int w = tid >> 6, lane = tid & 63;
    const int l15 = lane & 15, l4 = lane >> 4;
    const int m0 = blockIdx.x * 64, n0 = blockIdx.y * 64;

    f32x4 zero = {0.f, 0.f, 0.f, 0.f};
    f32x4 acc[4] = {zero, zero, zero, zero};

    for (int c = 0; c < nch; ++c) {
        int row = tid >> 2, seg = tid & 3;
        const u16* sa = ga.a[c] + (long)(m0 + row) * astr + seg * 16;
        *(uint4*)(&As[row * 72 + seg * 16])     = *(const uint4*)(sa);
        *(uint4*)(&As[row * 72 + seg * 16 + 8]) = *(const uint4*)(sa + 8);
        const u16* sb = ga.b[c] + (long)(n0 + row) * bstr + seg * 16;
        *(uint4*)(&Bs[row * 72 + seg * 16])     = *(const uint4*)(sb);
        *(uint4*)(&Bs[row * 72 + seg * 16 + 8]) = *(const uint4*)(sb + 8);
        __syncthreads();
        #pragma unroll
        for (int ks = 0; ks < 2; ++ks) {
            short8 bfrag = *(const short8*)(&Bs[(w * 16 + l15) * 72 + ks * 32 + l4 * 8]);
            #pragma unroll
            for (int rt = 0; rt < 4; ++rt) {
                short8 a = *(const short8*)(&As[(rt * 16 + l15) * 72 + ks * 32 + l4 * 8]);
                acc[rt] = mfma16(a, bfrag, acc[rt]);
            }
        }
        __syncthreads();
    }

    int n = n0 + w * 16 + l15;
    float bv = bias ? bias[n] : 0.f;
    #pragma unroll
    for (int rt = 0; rt < 4; ++rt) {
        #pragma unroll
        for (int i = 0; i < 4; ++i) {
            int m = m0 + rt * 16 + l4 * 4 + i;
            float v = acc[rt][i] + bv;
            if (mode == 0) {
                outf[(long)m * ldc + n] = v;
            } else {
                u16 h = f2bf(v);
                ohi[(long)m * ldc + n] = h;
                olo[(long)m * ldc + n] = f2bf(v - bf2f(h));
            }
        }
    }
}

// ---------- row softmax (1024 wide), f32 in/out -----------------------------
__global__ __launch_bounds__(256) void softmax_kernel(
    const float* __restrict__ lg, float* __restrict__ out)
{
    __shared__ float red[256];
    int row = blockIdx.x, tid = threadIdx.x;
    const float* src = lg + (long)row * 1024;
    float x[4];
    float mx = -1e30f;
    #pragma unroll
    for (int i = 0; i < 4; ++i) { x[i] = src[tid + 256 * i]; mx = fmaxf(mx, x[i]); }
    red[tid] = mx; __syncthreads();
    for (int s = 128; s > 0; s >>= 1) { if (tid < s) red[tid] = fmaxf(red[tid], red[tid + s]); __syncthreads(); }
    mx = red[0]; __syncthreads();
    float sm = 0.f;
    #pragma unroll
    for (int i = 0; i < 4; ++i) { x[i] = __expf(x[i] - mx); sm += x[i]; }
    red[tid] = sm; __syncthreads();
    for (int s = 128; s > 0; s >>= 1) { if (tid < s) red[tid] += red[tid + s]; __syncthreads(); }
    float inv = 1.f / red[0];
    float* dst = out + (long)row * 1024;
    #pragma unroll
    for (int i = 0; i < 4; ++i) dst[tid + 256 * i] = x[i] * inv;
}

// ---------------------------------------------------------------------------
extern "C" void kernel_launch(void* const* d_in, const int* in_sizes, int n_in,
                              void* d_out, int out_size, void* d_ws, size_t ws_size,
                              hipStream_t stream)
{
    const int* tok[3] = {(const int*)d_in[0], (const int*)d_in[1], (const int*)d_in[2]};
    const float *emb[3], *wih[3], *whh[3], *bih[3], *bhh[3];
    for (int g = 0; g < 3; ++g) {
        emb[g] = (const float*)d_in[3 + 5 * g];
        wih[g] = (const float*)d_in[4 + 5 * g];
        whh[g] = (const float*)d_in[5 + 5 * g];
        bih[g] = (const float*)d_in[6 + 5 * g];
        bhh[g] = (const float*)d_in[7 + 5 * g];
    }
    const float* lin_w = (const float*)d_in[18];
    const float* lin_b = (const float*)d_in[19];

    char* ws = (char*)d_ws;
    size_t off = 0;
    auto alloc = [&](size_t bytes) { void* p = ws + off; off += (bytes + 255) & ~255ull; return p; };

    const size_t BH  = (size_t)B_ * H_;           // 524288
    const size_t PRB = 3 * BH * 2;                // bf16 plane bytes (3.1 MB)
    const size_t PING = 2 * PRB;                  // h1+h2 per ping

    u16*   Xs   = (u16*)alloc(3ll * S_ * B_ * XW_ * 2);     // 100.7 MB
    u16*   Wswz = (u16*)alloc(3ll * WSZG * 2);              // 17.7 MB
    u16*   LW1  = (u16*)alloc((size_t)H_ * H_ * 2);
    u16*   LW2  = (u16*)alloc((size_t)H_ * H_ * 2);
    char*  HB   = (char*)alloc(2 * PING);                   // 12.6 MB
    u16*   QC1  = (u16*)alloc(BH * 2);
    u16*   QC2  = (u16*)alloc(BH * 2);
    u16*   EQ1  = (u16*)alloc(BH * 2);
    u16*   EQ2  = (u16*)alloc(BH * 2);
    float* LG   = (float*)alloc(3ll * B_ * B_ * 4);         // 12.6 MB

    u16* H1[2]; u16* H2[2];
    for (int i = 0; i < 2; ++i) {
        char* pb = HB + (size_t)i * PING;
        H1[i] = (u16*)pb;
        H2[i] = (u16*)(pb + PRB);
    }

    hipMemsetAsync(HB, 0, PING, stream);   // zero h0 (ping 0: both planes)

    for (int g = 0; g < 3; ++g) {
        gather_kernel<<<dim3(S_ * B_ / 8), 256, 0, stream>>>(tok[g], emb[g], Xs + (size_t)g * S_ * B_ * XW_);
        repack_swz<<<dim3(WSZG / 256), 256, 0, stream>>>(wih[g], whh[g], Wswz + (size_t)g * WSZG);
    }
    repack_lin<<<dim3(H_ * H_ / 256), 256, 0, stream>>>(lin_w, LW1, LW2);

    BiasPtrs bp;
    for (int g = 0; g < 3; ++g) { bp.bih[g] = bih[g]; bp.bhh[g] = bhh[g]; }

    int p = 0;
    for (int t = S_ - 1; t >= 0; --t) {
        gru_step<<<dim3(16, 16, 3), 256, 0, stream>>>(Xs, Wswz, bp,
            H1[p], H2[p], H1[1 - p], H2[1 - p], t);
        p ^= 1;
    }
    const u16* H1F = H1[p];
    const u16* H2F = H2[p];

    qc_kernel<<<dim3(BH / 256), 256, 0, stream>>>(H1F, H2F, QC1, QC2);

    // eqc = qc @ lin_w.T + lin_b : q1w1 + q2w1 + q1w2 (24 chunks over K=512)
    GArgs ga;
    for (int c = 0; c < 8; ++c)   { ga.a[c] = QC1 + c * 64;        ga.b[c] = LW1 + c * 64; }
    for (int c = 8; c < 16; ++c)  { ga.a[c] = QC2 + (c - 8) * 64;  ga.b[c] = LW1 + (c - 8) * 64; }
    for (int c = 16; c < 24; ++c) { ga.a[c] = QC1 + (c - 16) * 64; ga.b[c] = LW2 + (c - 16) * 64; }
    gemm_nt<<<dim3(16, 8), 256, 0, stream>>>(ga, 24, H_, H_, lin_b, nullptr, EQ1, EQ2, H_, 1);

    // sims: logits = X @ er.T via a1b1 + a2b1 + a1b2
    const u16* R1 = H1F + 2 * BH;
    const u16* R2 = H2F + 2 * BH;
    for (int g = 0; g < 3; ++g) {
        const u16 *A1, *A2;
        if (g == 0)      { A1 = H1F;      A2 = H2F; }
        else if (g == 1) { A1 = H1F + BH; A2 = H2F + BH; }
        else             { A1 = EQ1;      A2 = EQ2; }
        GArgs gs;
        for (int c = 0; c < 8; ++c)   { gs.a[c] = A1 + c * 64;        gs.b[c] = R1 + c * 64; }
        for (int c = 8; c < 16; ++c)  { gs.a[c] = A2 + (c - 8) * 64;  gs.b[c] = R1 + (c - 8) * 64; }
        for (int c = 16; c < 24; ++c) { gs.a[c] = A1 + (c - 16) * 64; gs.b[c] = R2 + (c - 16) * 64; }
        gemm_nt<<<dim3(16, 16), 256, 0, stream>>>(gs, 24, H_, H_, nullptr,
            LG + (size_t)g * B_ * B_, nullptr, nullptr, B_, 0);
    }

    softmax_kernel<<<dim3(3 * B_), 256, 0, stream>>>(LG, (float*)d_out);
}